// Round 9
// baseline (40.251 us; speedup 1.0000x reference)
//
#include <hip/hip_runtime.h>
#include <math.h>

#define HW 256
#define TW 64
#define TH 32          // per block: 4 waves x 8 output rows
#define LW 68          // 2 halo + 64 + 2 halo (272B row stride, 16B-aligned)
#define WLH 12         // per-wave LDS rows: 8 output rows + 4 halo

__device__ __forceinline__ int reflect_idx(int i) {
    i = (i < 0) ? -i : i;
    i = (i >= HW) ? (2 * HW - 2 - i) : i;
    return i;
}

__device__ __forceinline__ float4 max4(float4 a, float4 b) {
    float4 r; r.x = fmaxf(a.x, b.x); r.y = fmaxf(a.y, b.y);
    r.z = fmaxf(a.z, b.z); r.w = fmaxf(a.w, b.w); return r;
}
__device__ __forceinline__ float4 max34(float4 a, float4 b, float4 c) {
    float4 r; r.x = fmaxf(fmaxf(a.x, b.x), c.x); r.y = fmaxf(fmaxf(a.y, b.y), c.y);
    r.z = fmaxf(fmaxf(a.z, b.z), c.z); r.w = fmaxf(fmaxf(a.w, b.w), c.w); return r;
}
__device__ __forceinline__ float4 add4(float4 a, float4 b) {
    float4 r; r.x = a.x + b.x; r.y = a.y + b.y;
    r.z = a.z + b.z; r.w = a.w + b.w; return r;
}
__device__ __forceinline__ float4 sub4(float4 a, float4 b) {
    float4 r; r.x = a.x - b.x; r.y = a.y - b.y;
    r.z = a.z - b.z; r.w = a.w - b.w; return r;
}

// One output row, 4 pixels. Window rows A0..B4 (A=cols0-3, B=cols4-7),
// column maxes cm, column sums cs. bp = beta*log2e; c04b = 0.04*bp.
__device__ __forceinline__ void proc_row(
    float4 A0, float4 B0, float4 A1, float4 B1, float4 A2, float4 B2,
    float4 A3, float4 B3, float4 A4, float4 B4,
    float4 cmA, float4 cmB, float4 csA, float4 csB,
    float bp, float c04b, float inv_bp, float lam,
    float* __restrict__ orow)
{
    const float cs[8] = {csA.x,csA.y,csA.z,csA.w, csB.x,csB.y,csB.z,csB.w};
    const float cm[8] = {cmA.x,cmA.y,cmA.z,cmA.w, cmB.x,cmB.y,cmB.z,cmB.w};
    const float vv[5][8] = {
        {A0.x,A0.y,A0.z,A0.w, B0.x,B0.y,B0.z,B0.w},
        {A1.x,A1.y,A1.z,A1.w, B1.x,B1.y,B1.z,B1.w},
        {A2.x,A2.y,A2.z,A2.w, B2.x,B2.y,B2.z,B2.w},
        {A3.x,A3.y,A3.z,A3.w, B3.x,B3.y,B3.z,B3.w},
        {A4.x,A4.y,A4.z,A4.w, B4.x,B4.y,B4.z,B4.w}};

    // Sliding horizontal sums of the 8 column sums (5-wide windows)
    const float t12 = cs[1] + cs[2];
    const float t34 = cs[3] + cs[4];
    const float t56 = cs[5] + cs[6];
    const float u   = t12 + t34;
    const float w_  = t34 + t56;
    const float S[4] = {cs[0] + u, u + cs[5], cs[2] + w_, w_ + cs[7]};

    // Horizontal max of 5 column-maxes with shared pairs (v_max3 fusion)
    const float h12 = fmaxf(cm[1], cm[2]);
    const float h34 = fmaxf(cm[3], cm[4]);
    const float h56 = fmaxf(cm[5], cm[6]);
    const float m[4] = {fmaxf(fmaxf(cm[0], h12), h34),
                        fmaxf(fmaxf(h12, h34), cm[5]),
                        fmaxf(fmaxf(cm[2], h34), h56),
                        fmaxf(fmaxf(h34, h56), cm[7])};

    float bm[4], ws[4], wa[4];
    #pragma unroll
    for (int p = 0; p < 4; ++p) { bm[p] = S[p] * c04b; ws[p] = 0.0f; wa[p] = 0.0f; }

    #pragma unroll
    for (int k = 0; k < 5; ++k) {
        #pragma unroll
        for (int j = 0; j < 5; ++j) {
            #pragma unroll
            for (int p = 0; p < 4; ++p) {
                const float tv = fmaf(bp, vv[k][p + j], -bm[p]);     // beta'*(v-mean)
                const float e  = __builtin_amdgcn_exp2f(-fabsf(tv)); // src-mod -|t|
                ws[p] += e;
                wa[p] = fmaf(e, tv, wa[p]);
            }
        }
    }

    float o[4];
    #pragma unroll
    for (int p = 0; p < 4; ++p) {
        const float mean = S[p] * 0.04f;
        const float med  = fmaf(wa[p] * __builtin_amdgcn_rcpf(ws[p]), inv_bp, mean);
        o[p] = fmaf(lam, med - m[p], m[p]);
    }
    float4 o4; o4.x = o[0]; o4.y = o[1]; o4.z = o[2]; o4.w = o[3];
    *(float4*)orow = o4;
}

__global__ __launch_bounds__(256, 4)
void maxmedian_kernel(const float* __restrict__ x,
                      const float* __restrict__ mix,
                      const float* __restrict__ beta_raw,
                      float* __restrict__ out,
                      int C) {
    // Per-wave private tiles: 4 waves x 12 rows x 68 cols (13 KB total).
    __shared__ __align__(16) float wtile[4][WLH * LW];

    const int tiles_x = HW / TW;                       // 4
    const int tiles_per_plane = tiles_x * (HW / TH);   // 32
    const int plane = blockIdx.x / tiles_per_plane;
    const int t     = blockIdx.x % tiles_per_plane;
    const int ty0 = (t / tiles_x) * TH;
    const int tx0 = (t % tiles_x) * TW;

    const float* __restrict__ xp = x + (size_t)plane * (HW * HW);
    const int tid  = threadIdx.x;
    const int wave = tid >> 6;       // 0..3
    const int lane = tid & 63;

    const int wy0 = ty0 + 8 * wave;  // wave's first output row
    float* __restrict__ wt = wtile[wave];

    // ---- Wave-private staging: 12 rows x 68 cols, reflect applied. NO barrier.
    {
        const int gx = tx0 + lane;   // main: col = lane (0..63)
        #pragma unroll
        for (int k = 0; k < WLH; ++k) {
            const int gy = reflect_idx(wy0 - 2 + k);
            wt[k * LW + lane + 2] = xp[gy * HW + gx];
        }
        if (lane < 48) {             // halo cols {0,1,66,67} x 12 rows
            const int jj = lane & 3;
            const int j  = (jj < 2) ? jj : (64 + jj);
            const int r  = lane >> 2;            // 0..11
            const int gx2 = reflect_idx(tx0 + j - 2);
            const int gy2 = reflect_idx(wy0 - 2 + r);
            wt[r * LW + j] = xp[gy2 * HW + gx2];
        }
    }
    // Pin program order: staging DS writes complete (lgkmcnt, auto-inserted)
    // before this wave's DS reads. No cross-wave dependency exists.
    __builtin_amdgcn_wave_barrier();

    // ---- Parameters ----
    const int ch = plane % C;
    const float lam  = 1.0f / (1.0f + __expf(-mix[ch]));
    const float beta = 5.0f + 45.0f / (1.0f + __expf(-beta_raw[0]));
    const float bp     = beta * 1.44269504088896f;   // beta * log2(e) > 0
    const float inv_bp = 1.0f / bp;
    const float c04b   = 0.04f * bp;

    // ---- Each lane: 4-wide x 2-tall within the wave's 8 rows ----
    const int tx  = lane & 15;       // 16 column groups
    const int ryq = lane >> 4;       // 0..3
    const int r0  = ryq * 2;         // 0,2,4,6 (wave-local)
    const float* lbase = &wt[r0 * LW + 4 * tx];

    float4 w0a = *(const float4*)(lbase + 0 * LW);
    float4 w0b = *(const float4*)(lbase + 0 * LW + 4);
    float4 w1a = *(const float4*)(lbase + 1 * LW);
    float4 w1b = *(const float4*)(lbase + 1 * LW + 4);
    float4 w2a = *(const float4*)(lbase + 2 * LW);
    float4 w2b = *(const float4*)(lbase + 2 * LW + 4);
    float4 w3a = *(const float4*)(lbase + 3 * LW);
    float4 w3b = *(const float4*)(lbase + 3 * LW + 4);
    float4 w4a = *(const float4*)(lbase + 4 * LW);
    float4 w4b = *(const float4*)(lbase + 4 * LW + 4);
    float4 w5a = *(const float4*)(lbase + 5 * LW);
    float4 w5b = *(const float4*)(lbase + 5 * LW + 4);

    float4 csA = add4(add4(add4(w0a, w1a), add4(w2a, w3a)), w4a);
    float4 csB = add4(add4(add4(w0b, w1b), add4(w2b, w3b)), w4b);

    const float4 p12a = max4(w1a, w2a), p12b = max4(w1b, w2b);
    const float4 p34a = max4(w3a, w4a), p34b = max4(w3b, w4b);
    const float4 cm0a = max34(w0a, p12a, p34a);
    const float4 cm0b = max34(w0b, p12b, p34b);

    float* __restrict__ orow =
        out + (size_t)plane * (HW * HW) + (size_t)(wy0 + r0) * HW + (tx0 + 4 * tx);

    proc_row(w0a,w0b, w1a,w1b, w2a,w2b, w3a,w3b, w4a,w4b,
             cm0a, cm0b, csA, csB, bp, c04b, inv_bp, lam, orow);

    csA = add4(csA, sub4(w5a, w0a));
    csB = add4(csB, sub4(w5b, w0b));
    const float4 cm1a = max34(p12a, p34a, w5a);
    const float4 cm1b = max34(p12b, p34b, w5b);

    proc_row(w1a,w1b, w2a,w2b, w3a,w3b, w4a,w4b, w5a,w5b,
             cm1a, cm1b, csA, csB, bp, c04b, inv_bp, lam, orow + HW);
}

extern "C" void kernel_launch(void* const* d_in, const int* in_sizes, int n_in,
                              void* d_out, int out_size, void* d_ws, size_t ws_size,
                              hipStream_t stream) {
    const float* x        = (const float*)d_in[0];
    const float* mix      = (const float*)d_in[1];
    const float* beta_raw = (const float*)d_in[2];
    float* out            = (float*)d_out;

    const int planes = in_sizes[0] / (HW * HW);                 // 128
    const int C      = in_sizes[1];                             // 32
    const int tiles_per_plane = (HW / TW) * (HW / TH);          // 32
    const int grid = planes * tiles_per_plane;                  // 4096

    maxmedian_kernel<<<grid, 256, 0, stream>>>(x, mix, beta_raw, out, C);
}

// Round 10
// 39.484 us; speedup vs baseline: 1.0194x; 1.0194x over previous
//
#include <hip/hip_runtime.h>
#include <math.h>

#define HW 256
#define TW 64
#define TH 32
#define LW 68           // 2 halo + 64 + 2 halo (272B row stride, 16B-aligned)
#define LH 36           // 2 halo + 32 + 2 halo

__device__ __forceinline__ int reflect_idx(int i) {
    i = (i < 0) ? -i : i;
    i = (i >= HW) ? (2 * HW - 2 - i) : i;
    return i;
}

__device__ __forceinline__ float4 max4(float4 a, float4 b) {
    float4 r; r.x = fmaxf(a.x, b.x); r.y = fmaxf(a.y, b.y);
    r.z = fmaxf(a.z, b.z); r.w = fmaxf(a.w, b.w); return r;
}
__device__ __forceinline__ float4 max34(float4 a, float4 b, float4 c) {
    float4 r; r.x = fmaxf(fmaxf(a.x, b.x), c.x); r.y = fmaxf(fmaxf(a.y, b.y), c.y);
    r.z = fmaxf(fmaxf(a.z, b.z), c.z); r.w = fmaxf(fmaxf(a.w, b.w), c.w); return r;
}
__device__ __forceinline__ float4 add4(float4 a, float4 b) {
    float4 r; r.x = a.x + b.x; r.y = a.y + b.y;
    r.z = a.z + b.z; r.w = a.w + b.w; return r;
}
__device__ __forceinline__ float4 sub4(float4 a, float4 b) {
    float4 r; r.x = a.x - b.x; r.y = a.y - b.y;
    r.z = a.z - b.z; r.w = a.w - b.w; return r;
}

__global__ __launch_bounds__(256, 4)
void maxmedian_kernel(const float* __restrict__ x,
                      const float* __restrict__ mix,
                      const float* __restrict__ beta_raw,
                      float* __restrict__ out,
                      int C) {
    __shared__ __align__(16) float tile[LH * LW];

    const int tiles_x = HW / TW;                       // 4
    const int tiles_per_plane = tiles_x * (HW / TH);   // 32
    const int plane = blockIdx.x / tiles_per_plane;
    const int t     = blockIdx.x % tiles_per_plane;
    const int ty0 = (t / tiles_x) * TH;
    const int tx0 = (t % tiles_x) * TW;

    const float* __restrict__ xp = x + (size_t)plane * (HW * HW);
    const int tid = threadIdx.x;

    // ---- Stage (TH+4) x (TW+4) with reflect padding ----
    {
        const int c   = tid & 63;
        const int r0s = tid >> 6;             // 0..3
        const int gx  = tx0 + c;
        #pragma unroll
        for (int k = 0; k < 9; ++k) {
            const int r  = r0s + 4 * k;       // 0..35
            const int gy = reflect_idx(ty0 + r - 2);
            tile[r * LW + c + 2] = xp[gy * HW + gx];
        }
        if (tid < 144) {                      // cols {0,1,66,67} x 36 rows
            const int jj = tid & 3;
            const int j  = (jj < 2) ? jj : (64 + jj);
            const int r  = tid >> 2;
            const int gx2 = reflect_idx(tx0 + j - 2);
            const int gy2 = reflect_idx(ty0 + r - 2);
            tile[r * LW + j] = xp[gy2 * HW + gx2];
        }
    }
    __syncthreads();

    // ---- Parameters ----
    const int ch = plane % C;
    const float lam  = 1.0f / (1.0f + __expf(-mix[ch]));
    const float beta = 5.0f + 45.0f / (1.0f + __expf(-beta_raw[0]));
    const float bp     = beta * 1.44269504088896f;   // beta * log2(e) > 0
    const float inv_bp = 1.0f / bp;
    const float c04b   = 0.04f * bp;

    // ---- Each thread: 4-wide x 2-tall, both rows merged into ONE tap loop ----
    const int tx  = tid & 15;
    const int ryq = tid >> 4;        // 0..15
    const int r0  = ryq * 2;
    const float* lbase = &tile[r0 * LW + 4 * tx];

    const float4 w0a = *(const float4*)(lbase + 0 * LW);
    const float4 w0b = *(const float4*)(lbase + 0 * LW + 4);
    const float4 w1a = *(const float4*)(lbase + 1 * LW);
    const float4 w1b = *(const float4*)(lbase + 1 * LW + 4);
    const float4 w2a = *(const float4*)(lbase + 2 * LW);
    const float4 w2b = *(const float4*)(lbase + 2 * LW + 4);
    const float4 w3a = *(const float4*)(lbase + 3 * LW);
    const float4 w3b = *(const float4*)(lbase + 3 * LW + 4);
    const float4 w4a = *(const float4*)(lbase + 4 * LW);
    const float4 w4b = *(const float4*)(lbase + 4 * LW + 4);
    const float4 w5a = *(const float4*)(lbase + 5 * LW);
    const float4 w5b = *(const float4*)(lbase + 5 * LW + 4);

    // Column sums for row0 window (rows 0-4); row1 = row0 + w5 - w0.
    const float4 cs0A = add4(add4(add4(w0a, w1a), add4(w2a, w3a)), w4a);
    const float4 cs0B = add4(add4(add4(w0b, w1b), add4(w2b, w3b)), w4b);
    const float4 cs1A = add4(cs0A, sub4(w5a, w0a));
    const float4 cs1B = add4(cs0B, sub4(w5b, w0b));

    // Column maxes with shared vertical pairs.
    const float4 p12a = max4(w1a, w2a), p12b = max4(w1b, w2b);
    const float4 p34a = max4(w3a, w4a), p34b = max4(w3b, w4b);
    const float4 cm0A = max34(w0a, p12a, p34a);
    const float4 cm0B = max34(w0b, p12b, p34b);
    const float4 cm1A = max34(p12a, p34a, w5a);
    const float4 cm1B = max34(p12b, p34b, w5b);

    const float vv[6][8] = {
        {w0a.x,w0a.y,w0a.z,w0a.w, w0b.x,w0b.y,w0b.z,w0b.w},
        {w1a.x,w1a.y,w1a.z,w1a.w, w1b.x,w1b.y,w1b.z,w1b.w},
        {w2a.x,w2a.y,w2a.z,w2a.w, w2b.x,w2b.y,w2b.z,w2b.w},
        {w3a.x,w3a.y,w3a.z,w3a.w, w3b.x,w3b.y,w3b.z,w3b.w},
        {w4a.x,w4a.y,w4a.z,w4a.w, w4b.x,w4b.y,w4b.z,w4b.w},
        {w5a.x,w5a.y,w5a.z,w5a.w, w5b.x,w5b.y,w5b.z,w5b.w}};
    const float cs0[8] = {cs0A.x,cs0A.y,cs0A.z,cs0A.w, cs0B.x,cs0B.y,cs0B.z,cs0B.w};
    const float cs1[8] = {cs1A.x,cs1A.y,cs1A.z,cs1A.w, cs1B.x,cs1B.y,cs1B.z,cs1B.w};
    const float cm0[8] = {cm0A.x,cm0A.y,cm0A.z,cm0A.w, cm0B.x,cm0B.y,cm0B.z,cm0B.w};
    const float cm1[8] = {cm1A.x,cm1A.y,cm1A.z,cm1A.w, cm1B.x,cm1B.y,cm1B.z,cm1B.w};

    // Sliding horizontal sums / maxes for both rows.
    float S0[4], S1[4], m0[4], m1[4];
    {
        const float a12 = cs0[1] + cs0[2], a34 = cs0[3] + cs0[4], a56 = cs0[5] + cs0[6];
        const float au = a12 + a34, aw = a34 + a56;
        S0[0] = cs0[0] + au; S0[1] = au + cs0[5]; S0[2] = cs0[2] + aw; S0[3] = aw + cs0[7];
        const float b12 = cs1[1] + cs1[2], b34 = cs1[3] + cs1[4], b56 = cs1[5] + cs1[6];
        const float bu = b12 + b34, bw = b34 + b56;
        S1[0] = cs1[0] + bu; S1[1] = bu + cs1[5]; S1[2] = cs1[2] + bw; S1[3] = bw + cs1[7];

        const float h12 = fmaxf(cm0[1], cm0[2]);
        const float h34 = fmaxf(cm0[3], cm0[4]);
        const float h56 = fmaxf(cm0[5], cm0[6]);
        m0[0] = fmaxf(fmaxf(cm0[0], h12), h34);
        m0[1] = fmaxf(fmaxf(h12, h34), cm0[5]);
        m0[2] = fmaxf(fmaxf(cm0[2], h34), h56);
        m0[3] = fmaxf(fmaxf(h34, h56), cm0[7]);
        const float g12 = fmaxf(cm1[1], cm1[2]);
        const float g34 = fmaxf(cm1[3], cm1[4]);
        const float g56 = fmaxf(cm1[5], cm1[6]);
        m1[0] = fmaxf(fmaxf(cm1[0], g12), g34);
        m1[1] = fmaxf(fmaxf(g12, g34), cm1[5]);
        m1[2] = fmaxf(fmaxf(cm1[2], g34), g56);
        m1[3] = fmaxf(fmaxf(g34, g56), cm1[7]);
    }

    float bm0[4], bm1[4], ws0[4], wa0[4], ws1[4], wa1[4];
    #pragma unroll
    for (int p = 0; p < 4; ++p) {
        bm0[p] = S0[p] * c04b; ws0[p] = 0.0f; wa0[p] = 0.0f;
        bm1[p] = S1[p] * c04b; ws1[p] = 0.0f; wa1[p] = 0.0f;
    }

    // Merged 25-tap loop: 8 pixels (two rows) per tap -> 16 independent chains.
    #pragma unroll
    for (int k = 0; k < 5; ++k) {
        #pragma unroll
        for (int j = 0; j < 5; ++j) {
            #pragma unroll
            for (int p = 0; p < 4; ++p) {
                const float v0  = vv[k][p + j];
                const float tv0 = fmaf(bp, v0, -bm0[p]);
                const float e0  = __builtin_amdgcn_exp2f(-fabsf(tv0));
                ws0[p] += e0;
                wa0[p] = fmaf(e0, tv0, wa0[p]);

                const float v1  = vv[k + 1][p + j];
                const float tv1 = fmaf(bp, v1, -bm1[p]);
                const float e1  = __builtin_amdgcn_exp2f(-fabsf(tv1));
                ws1[p] += e1;
                wa1[p] = fmaf(e1, tv1, wa1[p]);
            }
        }
    }

    float* __restrict__ orow =
        out + (size_t)plane * (HW * HW) + (size_t)(ty0 + r0) * HW + (tx0 + 4 * tx);

    float o0[4], o1[4];
    #pragma unroll
    for (int p = 0; p < 4; ++p) {
        const float mean0 = S0[p] * 0.04f;
        const float med0  = fmaf(wa0[p] * __builtin_amdgcn_rcpf(ws0[p]), inv_bp, mean0);
        o0[p] = fmaf(lam, med0 - m0[p], m0[p]);
        const float mean1 = S1[p] * 0.04f;
        const float med1  = fmaf(wa1[p] * __builtin_amdgcn_rcpf(ws1[p]), inv_bp, mean1);
        o1[p] = fmaf(lam, med1 - m1[p], m1[p]);
    }
    float4 q0; q0.x = o0[0]; q0.y = o0[1]; q0.z = o0[2]; q0.w = o0[3];
    float4 q1; q1.x = o1[0]; q1.y = o1[1]; q1.z = o1[2]; q1.w = o1[3];
    *(float4*)orow = q0;
    *(float4*)(orow + HW) = q1;
}

extern "C" void kernel_launch(void* const* d_in, const int* in_sizes, int n_in,
                              void* d_out, int out_size, void* d_ws, size_t ws_size,
                              hipStream_t stream) {
    const float* x        = (const float*)d_in[0];
    const float* mix      = (const float*)d_in[1];
    const float* beta_raw = (const float*)d_in[2];
    float* out            = (float*)d_out;

    const int planes = in_sizes[0] / (HW * HW);                 // 128
    const int C      = in_sizes[1];                             // 32
    const int tiles_per_plane = (HW / TW) * (HW / TH);          // 32
    const int grid = planes * tiles_per_plane;                  // 4096

    maxmedian_kernel<<<grid, 256, 0, stream>>>(x, mix, beta_raw, out, C);
}